// Round 10
// baseline (1068.107 us; speedup 1.0000x reference)
//
#include <hip/hip_runtime.h>

#define VOCAB   32000
#define WORDVEC 256
#define HIDDEN  512
#define TSTEPS  256
#define NBATCH  16
#define NROWS   (TSTEPS*NBATCH)   // 4096
#define GATES   (4*HIDDEN)        // 2048
#define NVB     125               // 32000/256
#define NWG     32                // LSTM worker WGs (32 x 16 hidden units)
#define NVBLK   8000              // vocab blocks (64 bm x 125 bn)
#define SPINCAP (1<<16)           // bounded readiness spin (escape hatch)

typedef __attribute__((ext_vector_type(8))) short short8;
typedef __attribute__((ext_vector_type(4))) float f32x4;
typedef unsigned long long u64;

#define AGLOAD(p) __hip_atomic_load((p), __ATOMIC_RELAXED, __HIP_MEMORY_SCOPE_AGENT)
#define MFMA16(a,b,c) __builtin_amdgcn_mfma_f32_16x16x32_bf16((a),(b),(c),0,0,0)

__device__ __forceinline__ unsigned short f2bf(float x){
    union { float f; unsigned int u; } v; v.f = x;
    unsigned int r = v.u + 0x7fffu + ((v.u >> 16) & 1u);
    return (unsigned short)(r >> 16);
}

// ---------------------------------------------------------------- K_prep:
// One launch, four independent jobs selected by blockIdx.x:
//   [0,512)     embed_xw : xw[r=t*16+n][k] = b[k] + W_embed[tok]@Wx
//   [512,544)   whp_prep : Wh -> per-WG MFMA-B-fragment bf16 image
//   [544,560)   hg_init  : h_0 -> tagged-pair exchange buffer 0 (+chunkcnt=0)
//   [560,4560)  wv_pack  : W_vocab -> MFMA-B-fragment-linear bf16
__global__ __launch_bounds__(256) void prep_all(const int* __restrict__ captions,
        const float* __restrict__ Wemb, const float* __restrict__ Wx,
        const float* __restrict__ b, float* __restrict__ xw,
        const float* __restrict__ Wh, unsigned short* __restrict__ Whp,
        const float* __restrict__ h_init, u64* __restrict__ hx,
        const float* __restrict__ Wv, unsigned short* __restrict__ WvP,
        int* __restrict__ chunkcnt){
    __shared__ float s[64][65];    // wv role (16.6 KB) -- also covers xs (8 KB)
    float (*xs)[WORDVEC] = (float(*)[WORDVEC])s;
    __shared__ int toks[8];
    int bid = blockIdx.x;
    int tid = threadIdx.x;
    if (bid < 512){
        // ---------------- embed_xw ----------------
        int r0 = bid * 8;
        if (tid < 8){
            int r = r0 + tid; int t = r >> 4, n = r & 15;
            toks[tid] = captions[n*257 + t];
        }
        __syncthreads();
        for (int i = 0; i < 8; ++i){
            int lin = tid + i*256;
            int ri = lin >> 8, d = lin & 255;
            xs[ri][d] = Wemb[(long)toks[ri]*WORDVEC + d];
        }
        __syncthreads();
        float4 b0 = *(const float4*)(b + tid*4);
        float4 b1 = *(const float4*)(b + 1024 + tid*4);
        float acc[8][8];
        for (int ri = 0; ri < 8; ++ri){
            acc[ri][0]=b0.x; acc[ri][1]=b0.y; acc[ri][2]=b0.z; acc[ri][3]=b0.w;
            acc[ri][4]=b1.x; acc[ri][5]=b1.y; acc[ri][6]=b1.z; acc[ri][7]=b1.w;
        }
        for (int d = 0; d < WORDVEC; ++d){
            float4 w0 = *(const float4*)(Wx + (long)d*GATES + tid*4);
            float4 w1 = *(const float4*)(Wx + (long)d*GATES + 1024 + tid*4);
            #pragma unroll
            for (int ri = 0; ri < 8; ++ri){
                float xv = xs[ri][d];
                acc[ri][0] += xv*w0.x; acc[ri][1] += xv*w0.y;
                acc[ri][2] += xv*w0.z; acc[ri][3] += xv*w0.w;
                acc[ri][4] += xv*w1.x; acc[ri][5] += xv*w1.y;
                acc[ri][6] += xv*w1.z; acc[ri][7] += xv*w1.w;
            }
        }
        for (int ri = 0; ri < 8; ++ri){
            float4 o0 = {acc[ri][0],acc[ri][1],acc[ri][2],acc[ri][3]};
            float4 o1 = {acc[ri][4],acc[ri][5],acc[ri][6],acc[ri][7]};
            *(float4*)(xw + (long)(r0+ri)*GATES + tid*4) = o0;
            *(float4*)(xw + (long)(r0+ri)*GATES + 1024 + tid*4) = o1;
        }
    } else if (bid < 544){
        // ---------------- whp_prep ----------------
        int w = bid - 512;
        for (int item = tid; item < 4096; item += 256){
            int f = item >> 6;          // 0..63
            int L = item & 63;
            int kt = f >> 2, nt = f & 3;
            int q = L >> 4, ln = L & 15;
            int col = nt*HIDDEN + w*16 + ln;   // gate nt, unit w*16+ln
            short8 vvec;
            for (int jj = 0; jj < 8; ++jj){
                int k = kt*32 + q*8 + jj;
                vvec[jj] = (short)f2bf(Wh[(long)k*GATES + col]);
            }
            *(short8*)(Whp + ((long)w*4096 + item)*8) = vvec;
        }
    } else if (bid < 560){
        // ---------------- hg_init (+ chunk counters zero) ----------------
        if (bid == 544 && tid < 16) chunkcnt[tid] = 0;
        int p = (bid - 544)*256 + tid;   // 4096 pairs
        int fq = p >> 6;
        int j  = (p & 3) * 2;
        int u0 = (fq>>2)*32 + (fq&3)*8 + j;
        u64 pk = (u64)f2bf(h_init[u0]) | ((u64)f2bf(h_init[u0+1]) << 16);   // tag 0
        hx[p] = pk;
    } else {
        // ---------------- wv_pack ----------------
        int tile = bid - 560;               // 0..3999
        int v0 = (tile >> 3) * 64;          // 500 column-tiles
        int k0 = (tile & 7) * 64;           // 8 row-tiles
        for (int i = 0; i < 16; ++i){
            int lin = tid + i*256;
            int kk = lin >> 6, vv = lin & 63;
            s[kk][vv] = Wv[(long)(k0+kk)*VOCAB + v0 + vv];
        }
        __syncthreads();
        for (int i = 0; i < 2; ++i){
            int lr = tid + i*256;          // 0..511 lane-rows
            int f  = lr >> 6;              // 0..7: vbl(0..3) x ktl(0..1)
            int vbl = f >> 1, ktl = f & 1;
            int L = lr & 63, q = L >> 4, ln = L & 15;
            short8 o;
            #pragma unroll
            for (int j = 0; j < 8; ++j)
                o[j] = (short)f2bf(s[ktl*32 + q*8 + j][vbl*16 + ln]);
            long vb = (long)(tile >> 3)*4 + vbl;
            long kt = (long)(tile & 7)*2 + ktl;
            *(short8*)(WvP + ((vb*16 + kt)*64 + L)*8) = o;
        }
    }
}

// ---------------------------------------------------------------- K2:
// Fused LSTM + vocab GEMM, round 10.
//   - hsP rows are now T-MAJOR: GEMM row rg = t*16 + n. Each vocab block's
//     64 rows span only 4 t-values -> ready after chunk bm>>2 (16 cohorts
//     of 500 blocks instead of 4 of 2000: last-cohort tail ~20us not ~85us).
//   - readiness via per-chunk arrival counters chunkcnt[c] (lstm tid0
//     atomicAdd after drain+barrier); vocab polls ONE address == 32.
//   - lstm poll gets a cheap HINT phase (1 pair per publisher WG, 2KB/round
//     vs 32KB/round) before the unchanged full tag-verify read.
__global__ __launch_bounds__(256) void lstm_vocab(const float* __restrict__ xw,
        const unsigned short* __restrict__ Whp, u64* __restrict__ hx,
        unsigned short* __restrict__ hsP, int* __restrict__ chunkcnt,
        const unsigned short* __restrict__ WvP, const float* __restrict__ bvoc,
        const int* __restrict__ captions, float* __restrict__ pmax,
        float* __restrict__ psum, float* __restrict__ tlog){
    __shared__ unsigned int hstage[4096];   // 16 KB (lstm role)
    __shared__ float a_s[4][16][16];        // 4 KB  (lstm role)
    __shared__ int   tgt_s[64];             // vocab role
    __shared__ float wmax_s[4][64], wsum_s[4][64];
    int tid = threadIdx.x;       // 0..255

    if (blockIdx.x >= NWG){
        // ================= vocab role =================
        int vid = blockIdx.x - NWG;         // 0..7999
        int bm  = vid / 125;                // ready-order: bm ascending
        int bn  = vid % 125;
        int needc = bm >> 2;                // chunk whose completion releases us

        if (tid == 0){
            int cnt = 0;
            while (AGLOAD(&chunkcnt[needc]) < NWG){
                __builtin_amdgcn_s_sleep(8);
                if (++cnt > SPINCAP) break;   // escape hatch (never in practice)
            }
        }
        __syncthreads();

        int wv = tid >> 6, L = tid & 63;
        int q = L >> 4, ln = L & 15;
        if (tid < 64){
            int rg = bm*64 + tid;           // rg = t*16 + n
            tgt_s[tid] = captions[(rg & 15)*257 + (rg >> 4) + 1];
        }
        __syncthreads();
        f32x4 acc[4][4];
        for (int mt=0;mt<4;++mt) for (int nt=0;nt<4;++nt) acc[mt][nt] = (f32x4){0.f,0.f,0.f,0.f};
        int colb = bn*256 + wv*64;
        // u16 bases incl. lane offset; frag stride 512 u16 (1KB), mt/nt stride 8192 u16
        const unsigned short* aB = hsP + ((long)(bm*4)*16)*512 + (long)L*8;
        const unsigned short* bB = WvP + ((long)(bn*16 + wv*4)*16)*512 + (long)L*8;
        #pragma unroll 1
        for (int kt = 0; kt < 16; ++kt){
            const short8* aK = (const short8*)(aB + (long)kt*512);   // short8 idx: *16B
            const short8* bK = (const short8*)(bB + (long)kt*512);
            // G(m01,n01)
            short8 a0 = aK[0],    a1 = aK[1024];
            short8 b0 = bK[0],    b1 = bK[1024];
            acc[0][0] = MFMA16(a0,b0,acc[0][0]); acc[0][1] = MFMA16(a0,b1,acc[0][1]);
            acc[1][0] = MFMA16(a1,b0,acc[1][0]); acc[1][1] = MFMA16(a1,b1,acc[1][1]);
            __builtin_amdgcn_sched_barrier(0);
            // G(m01,n23): reuse a0,a1
            short8 b2 = bK[2048], b3 = bK[3072];
            acc[0][2] = MFMA16(a0,b2,acc[0][2]); acc[0][3] = MFMA16(a0,b3,acc[0][3]);
            acc[1][2] = MFMA16(a1,b2,acc[1][2]); acc[1][3] = MFMA16(a1,b3,acc[1][3]);
            __builtin_amdgcn_sched_barrier(0);
            // G(m23,n23): reuse b2,b3
            short8 a2 = aK[2048], a3 = aK[3072];
            acc[2][2] = MFMA16(a2,b2,acc[2][2]); acc[2][3] = MFMA16(a2,b3,acc[2][3]);
            acc[3][2] = MFMA16(a3,b2,acc[3][2]); acc[3][3] = MFMA16(a3,b3,acc[3][3]);
            __builtin_amdgcn_sched_barrier(0);
            // G(m23,n01): reuse a2,a3; reload b0,b1 via opaque addr (liveness cap)
            u64 bKo = (u64)bK; asm volatile("" : "+v"(bKo));
            const short8* bK2 = (const short8*)bKo;
            short8 c0 = bK2[0], c1 = bK2[1024];
            acc[2][0] = MFMA16(a2,c0,acc[2][0]); acc[2][1] = MFMA16(a2,c1,acc[2][1]);
            acc[3][0] = MFMA16(a3,c0,acc[3][0]); acc[3][1] = MFMA16(a3,c1,acc[3][1]);
            __builtin_amdgcn_sched_barrier(0);
        }
        float bv[4];
        #pragma unroll
        for (int nt=0;nt<4;++nt) bv[nt] = bvoc[colb + nt*16 + ln];
        #pragma unroll
        for (int mt=0;mt<4;++mt) for (int nt=0;nt<4;++nt) for (int r=0;r<4;++r)
            acc[mt][nt][r] += bv[nt];
        // target-logit grab — fully STATIC (mt,nt,r) sweep; tg == nt*16+ln
        #pragma unroll
        for (int mt=0;mt<4;++mt)
            #pragma unroll
            for (int nt=0;nt<4;++nt)
                #pragma unroll
                for (int r=0;r<4;++r){
                    int rl = mt*16 + q*4 + r;
                    int tg = tgt_s[rl] - colb;
                    if (tg == nt*16 + ln) tlog[bm*64 + rl] = acc[mt][nt][r];
                }
        // per-row max & sumexp over this block's 256 cols
        #pragma unroll
        for (int mt=0;mt<4;++mt){
            #pragma unroll
            for (int r=0;r<4;++r){
                float m = fmaxf(fmaxf(acc[mt][0][r],acc[mt][1][r]), fmaxf(acc[mt][2][r],acc[mt][3][r]));
                for (int d=1; d<16; d<<=1) m = fmaxf(m, __shfl_xor(m, d, 16));
                float s = __expf(acc[mt][0][r]-m) + __expf(acc[mt][1][r]-m)
                        + __expf(acc[mt][2][r]-m) + __expf(acc[mt][3][r]-m);
                for (int d=1; d<16; d<<=1) s += __shfl_xor(s, d, 16);
                if (ln == 0){ int rl = mt*16 + q*4 + r; wmax_s[wv][rl] = m; wsum_s[wv][rl] = s; }
            }
        }
        __syncthreads();
        if (tid < 64){
            float M = fmaxf(fmaxf(wmax_s[0][tid],wmax_s[1][tid]), fmaxf(wmax_s[2][tid],wmax_s[3][tid]));
            float S = 0.f;
            for (int ww=0; ww<4; ++ww) S += wsum_s[ww][tid]*__expf(wmax_s[ww][tid]-M);
            pmax[(long)bn*NROWS + bm*64 + tid] = M;
            psum[(long)bn*NROWS + bm*64 + tid] = S;
        }
        return;
    }

    // ================= lstm role (round-1 protocol + hint poll) =================
    int w = blockIdx.x;          // 0..31
    int wv = tid >> 6;           // wave = gate = N-tile (0..3)
    int L = tid & 63;
    int q = L >> 4, ln = L & 15;
    int s_idx = tid >> 4, jl = tid & 15;   // (sequence, local hidden unit)

    // Wh B-fragments -> registers (wave wv uses fragments kt*4+wv only)
    short8 bw[16];
    #pragma unroll
    for (int kt = 0; kt < 16; ++kt)
        bw[kt] = *(const short8*)(Whp + ((long)w*4096 + (kt*4+wv)*64 + L)*8);

    float c_r = 0.f;
    int fq_pub = (w>>1)*4 + (w&1)*2 + (jl>>3);
    int pubIdx = fq_pub*64 + s_idx*4 + ((jl>>1)&3);
    int kt_h = w >> 1;
    int q_h  = ((w & 1) << 1) | (jl >> 3);
    int j_h  = jl & 7;
    unsigned int* hsP32 = (unsigned int*)hsP;
    // hint: pair 0 of publisher WG (tid&31) -> idx = fq(w',jl=0)*64
    int ww_ = tid & 31;
    int hintIdx = ((ww_>>1)*4 + (ww_&1)*2)*64;

    for (int t = 0; t < TSTEPS; ++t){
        // xw loads first: HBM latency overlaps the poll
        long xb = (long)(t*16 + s_idx)*GATES + w*16 + jl;
        float xg0 = xw[xb], xg1 = xw[xb+512], xg2 = xw[xb+1024], xg3 = xw[xb+1536];

        const u64* hr = hx + (t & 1)*4096;
        u64*       hw = hx + ((t+1) & 1)*4096;

        // ---- hint poll: 1 pair per publisher WG (cheap), then full verify
        {
            const u64* hintp = hr + hintIdx;
            for (;;){
                u64 hv_ = AGLOAD(hintp);
                if (__all((unsigned)(hv_ >> 32) == (unsigned)t)) break;
            }
        }
        // ---- full read + tag-verify (unchanged verified protocol)
        u64 v[16];
        #pragma unroll
        for (int i = 0; i < 16; ++i)
            v[i] = AGLOAD(hr + tid + i*256);
        for (;;){
            u64 bad = 0;
            #pragma unroll
            for (int i = 0; i < 16; ++i) bad |= (v[i] >> 32) ^ (u64)(unsigned)t;
            if (!bad) break;
            #pragma unroll
            for (int i = 0; i < 16; ++i)
                v[i] = AGLOAD(hr + tid + i*256);
        }
        #pragma unroll
        for (int i = 0; i < 16; ++i) hstage[tid + i*256] = (unsigned)v[i];
        __syncthreads();   // S1: stage complete (also orders vs prev a_s reads)

        // ---- MFMA: A-frag (kt,q,ln) = 4 contiguous u32 (linear sweep)
        f32x4 acc = {0.f,0.f,0.f,0.f};
        #pragma unroll
        for (int kt = 0; kt < 16; ++kt){
            short8 a = *(const short8*)((const unsigned short*)hstage + (kt*256 + q*64 + ln*4)*2);
            acc = MFMA16(a, bw[kt], acc);
        }
        #pragma unroll
        for (int r = 0; r < 4; ++r) a_s[wv][q*4 + r][ln] = acc[r];
        __syncthreads();   // S2: a_s complete (also: all hstage reads done)

        // ---- gate phase
        float ai = a_s[0][s_idx][jl] + xg0;
        float af = a_s[1][s_idx][jl] + xg1;
        float ao = a_s[2][s_idx][jl] + xg2;
        float ag = a_s[3][s_idx][jl] + xg3;
        float ig = 1.f/(1.f + __expf(-ai));
        float fg = 1.f/(1.f + __expf(-af));
        float og = 1.f/(1.f + __expf(-ao));
        float gg = 2.f/(1.f + __expf(-2.f*ag)) - 1.f;
        c_r = fg*c_r + ig*gg;
        float hv = og * (2.f/(1.f + __expf(-2.f*c_r)) - 1.f);
        unsigned short hb = f2bf(hv);

        // ---- publish h (tagged u64) + hsP (agent u32 pair, T-MAJOR rows)
        int hv32 = (int)hb;
        int other = __shfl(hv32, L ^ 1);
        if ((jl & 1) == 0){
            u64 pk = (u64)(unsigned short)hv32
                   | ((u64)(unsigned short)other << 16)
                   | ((u64)(unsigned)(t+1) << 32);
            __hip_atomic_store(hw + pubIdx, pk, __ATOMIC_RELAXED, __HIP_MEMORY_SCOPE_AGENT);
            unsigned int hp = (unsigned int)(unsigned short)hv32
                            | ((unsigned int)(unsigned short)other << 16);
            // fragment row-block rb = t; within-fragment lane ln = s_idx (n)
            __hip_atomic_store(hsP32 + (((long)(t*16 + kt_h))*64 + q_h*16 + s_idx)*4 + (j_h >> 1),
                               hp, __ATOMIC_RELAXED, __HIP_MEMORY_SCOPE_AGENT);
        }
        // ---- chunk boundary: drain stores, then arrive at chunk counter
        if ((t & 15) == 15){
            asm volatile("s_waitcnt vmcnt(0)" ::: "memory");
            __syncthreads();
            if (tid == 0) atomicAdd(&chunkcnt[t >> 4], 1);
        }
    }
}

// ---------------------------------------------------------------- K4:
// combine 125 partials per row -> lse -> masked NLL -> loss/N
// (row meaning is now rg = t*16 + n)
__global__ __launch_bounds__(256) void reduce_loss(const float* __restrict__ pmax,
        const float* __restrict__ psum, const float* __restrict__ tlog,
        const int* __restrict__ captions, float* __restrict__ out){
    int r = blockIdx.x*256 + threadIdx.x;
    float M = -1e30f;
    #pragma unroll 5
    for (int p=0;p<NVB;++p) M = fmaxf(M, pmax[(long)p*NROWS + r]);
    float S = 0.f;
    #pragma unroll 5
    for (int p=0;p<NVB;++p) S += psum[(long)p*NROWS + r]*__expf(pmax[(long)p*NROWS + r]-M);
    float lse = M + logf(S);
    float nll = lse - tlog[r];
    int tok = captions[(r & 15)*257 + (r >> 4) + 1];   // n = r&15, t = r>>4
    float val = (tok != 0) ? nll : 0.f;
    __shared__ float red[256];
    red[threadIdx.x] = val; __syncthreads();
    for (int s=128; s>0; s>>=1){
        if (threadIdx.x < s) red[threadIdx.x] += red[threadIdx.x+s];
        __syncthreads();
    }
    if (threadIdx.x == 0) atomicAdd(out, red[0] * (1.0f/16.0f));
}

// ---------------------------------------------------------------- launch
extern "C" void kernel_launch(void* const* d_in, const int* in_sizes, int n_in,
                              void* d_out, int out_size, void* d_ws, size_t ws_size,
                              hipStream_t stream){
    const int*   captions = (const int*)  d_in[0];
    const float* Wemb     = (const float*)d_in[1];
    const float* Wx       = (const float*)d_in[2];
    const float* Wh       = (const float*)d_in[3];
    const float* b        = (const float*)d_in[4];
    const float* Wv       = (const float*)d_in[5];
    const float* bvoc     = (const float*)d_in[6];
    const float* h_init   = (const float*)d_in[7];

    char* ws = (char*)d_ws;
    float*          xw   = (float*)         (ws + 0);          // 33554432 B
    unsigned short* WvP  = (unsigned short*)(ws + 33554432);   // 32768000 B
    unsigned short* hsP  = (unsigned short*)(ws + 66322432);   //  4194304 B
    float*          pmax = (float*)         (ws + 70516736);   //  2048000 B
    float*          psum = (float*)         (ws + 72564736);   //  2048000 B
    float*          tlog = (float*)         (ws + 74612736);   //    16384 B
    unsigned short* Whp  = (unsigned short*)(ws + 74629120);   //  2097152 B
    u64*            hx   = (u64*)           (ws + 76726272);   //    65536 B (2 bufs x 4096 u64)
    int*            cct  = (int*)           (ws + 76791808);   //       64 B (16 chunk ctrs)

    float* out_f = (float*)d_out;

    (void)hipMemsetAsync(d_out, 0, sizeof(float), stream);

    hipLaunchKernelGGL(prep_all,    dim3(4560),       dim3(256), 0, stream,
                       captions, Wemb, Wx, b, xw, Wh, Whp, h_init, hx, Wv, WvP, cct);
    hipLaunchKernelGGL(lstm_vocab,  dim3(NWG+NVBLK),  dim3(256), 0, stream,
                       xw, Whp, hx, hsP, cct, WvP, bvoc, captions, pmax, psum, tlog);
    hipLaunchKernelGGL(reduce_loss, dim3(16),         dim3(256), 0, stream,
                       pmax, psum, tlog, captions, out_f);
}